// Round 2
// baseline (373.256 us; speedup 1.0000x reference)
//
#include <hip/hip_runtime.h>
#include <math.h>

#define NUM_EMB 512
#define EMB_DIM 64
#define BB 16
#define TT 8192
#define CHUNK_K 128                 // codebook rows per LDS chunk (32 KB)
#define NCHUNK (NUM_EMB / CHUNK_K)

// Bit-exact replication of the numpy float32 reference:
//   A   = np.sum(xt*xt, -1)        -> pairwise_sum, 8 accumulators stride-8
//   E_k = np.einsum('btd,kd->btk') -> generic scalar sop: sequential
//         ascending-d  acc = fl(acc + fl(x_d * c_d))   (separate mul/add!)
//   C_k = np.sum(cb*cb, -1)        -> pairwise_sum, 8 accumulators
//   d_k = fl(fl(A - fl(2*E_k)) + C_k);  argmin = first occurrence.
// All rounding steps forced with __fmul_rn/__fadd_rn/__fsub_rn (never fma).
__global__ __launch_bounds__(256) void vq_np_kernel(
    const float* __restrict__ x,
    const float* __restrict__ cb,
    float* __restrict__ out) {
  __shared__ float c_lds[CHUNK_K * EMB_DIM];  // 32 KB chunk of codebook
  __shared__ float cn_lds[NUM_EMB];           // exact numpy-pairwise norms

  const int tid = threadIdx.x;
  const int p   = blockIdx.x * 256 + tid;     // position in [0, B*T)
  const int b   = p >> 13;
  const int t   = p & (TT - 1);

  // ---- C_k: numpy pairwise_sum(n=64): r[j]=sq[j]; r[j]+=sq[8i+j]; combine ----
  for (int k = tid; k < NUM_EMB; k += 256) {
    const float* row = cb + k * EMB_DIM;
    float r[8];
#pragma unroll
    for (int j = 0; j < 8; ++j) r[j] = __fmul_rn(row[j], row[j]);
#pragma unroll
    for (int i = 8; i < 64; i += 8)
#pragma unroll
      for (int j = 0; j < 8; ++j)
        r[j] = __fadd_rn(r[j], __fmul_rn(row[i + j], row[i + j]));
    cn_lds[k] = __fadd_rn(
        __fadd_rn(__fadd_rn(r[0], r[1]), __fadd_rn(r[2], r[3])),
        __fadd_rn(__fadd_rn(r[4], r[5]), __fadd_rn(r[6], r[7])));
  }

  // ---- x row into registers + A via the identical pairwise pattern ----
  float xr[EMB_DIM];
  const float* xb = x + (size_t)b * EMB_DIM * TT + t;
#pragma unroll
  for (int d = 0; d < EMB_DIM; ++d) xr[d] = xb[(size_t)d * TT];

  float A;
  {
    float r[8];
#pragma unroll
    for (int j = 0; j < 8; ++j) r[j] = __fmul_rn(xr[j], xr[j]);
#pragma unroll
    for (int i = 8; i < 64; i += 8)
#pragma unroll
      for (int j = 0; j < 8; ++j)
        r[j] = __fadd_rn(r[j], __fmul_rn(xr[i + j], xr[i + j]));
    A = __fadd_rn(
        __fadd_rn(__fadd_rn(r[0], r[1]), __fadd_rn(r[2], r[3])),
        __fadd_rn(__fadd_rn(r[4], r[5]), __fadd_rn(r[6], r[7])));
  }

  float dmin = INFINITY;
  int best = 0;

  for (int ch = 0; ch < NCHUNK; ++ch) {
    __syncthreads();
    {  // stage 32 KB codebook chunk into LDS (coalesced float4)
      const float4* src = (const float4*)(cb + ch * CHUNK_K * EMB_DIM);
      float4* dst = (float4*)c_lds;
#pragma unroll
      for (int j = 0; j < 8; ++j)
        dst[tid + j * 256] = src[tid + j * 256];
    }
    __syncthreads();

    const int kbase = ch * CHUNK_K;
    for (int kb = 0; kb < CHUNK_K; kb += 8) {
      // 8 codewords interleaved for ILP; each is a strictly sequential
      // ascending-d fp32 chain: acc = fl(acc + fl(x_d * c_d)).
      float acc[8];
#pragma unroll
      for (int j = 0; j < 8; ++j) acc[j] = 0.f;
#pragma unroll
      for (int d4 = 0; d4 < 16; ++d4) {
#pragma unroll
        for (int j = 0; j < 8; ++j) {
          const float4 c =
              *(const float4*)(c_lds + (kb + j) * EMB_DIM + d4 * 4);
          float a = acc[j];
          a = __fadd_rn(a, __fmul_rn(xr[d4 * 4 + 0], c.x));
          a = __fadd_rn(a, __fmul_rn(xr[d4 * 4 + 1], c.y));
          a = __fadd_rn(a, __fmul_rn(xr[d4 * 4 + 2], c.z));
          a = __fadd_rn(a, __fmul_rn(xr[d4 * 4 + 3], c.w));
          acc[j] = a;
        }
      }
#pragma unroll
      for (int j = 0; j < 8; ++j) {
        const int kk = kbase + kb + j;
        // d = fl(fl(A - fl(2*E)) + C)
        float dist = __fadd_rn(__fsub_rn(A, __fmul_rn(2.0f, acc[j])),
                               cn_lds[kk]);
        if (dist < dmin) { dmin = dist; best = kk; }  // first-occurrence min
      }
    }
  }

  // ---- gather winning codebook row, write both outputs ----
  const float4* qrow = (const float4*)(cb + best * EMB_DIM);
  float* o0 = out + (size_t)b * EMB_DIM * TT + t;
  float* o1 = o0 + (size_t)BB * EMB_DIM * TT;
#pragma unroll
  for (int j = 0; j < 16; ++j) {
    float4 q = qrow[j];
    size_t d0 = (size_t)(4 * j) * TT;
    o0[d0]          = q.x; o1[d0]          = q.x;
    o0[d0 + TT]     = q.y; o1[d0 + TT]     = q.y;
    o0[d0 + 2 * TT] = q.z; o1[d0 + 2 * TT] = q.z;
    o0[d0 + 3 * TT] = q.w; o1[d0 + 3 * TT] = q.w;
  }
}

extern "C" void kernel_launch(void* const* d_in, const int* in_sizes, int n_in,
                              void* d_out, int out_size, void* d_ws, size_t ws_size,
                              hipStream_t stream) {
  const float* x  = (const float*)d_in[0];   // [16, 64, 8192]
  const float* cb = (const float*)d_in[1];   // [512, 64]
  float* out = (float*)d_out;                // 2 x [16, 64, 8192]
  vq_np_kernel<<<(BB * TT) / 256, 256, 0, stream>>>(x, cb, out);
}

// Round 4
// 372.409 us; speedup vs baseline: 1.0023x; 1.0023x over previous
//
#include <hip/hip_runtime.h>
#include <math.h>

#define NUM_EMB 512
#define EMB_DIM 64
#define BB 16
#define TT 8192

typedef float vf4 __attribute__((ext_vector_type(4)));

// ---------------------------------------------------------------------------
// Kernel 1: numpy-pairwise codebook norms C_k -> workspace (so the main
// kernel can read them through the SCALAR path; LDS would force ds_read).
// np.sum(row*row, -1) for n=64 = pairwise_sum with 8 stride-8 accumulators,
// combined ((r0+r1)+(r2+r3))+((r4+r5)+(r6+r7)). All roundings explicit.
// ---------------------------------------------------------------------------
__global__ __launch_bounds__(256) void vq_norms(const float* __restrict__ cb,
                                                float* __restrict__ norms) {
  const int k = blockIdx.x * 256 + threadIdx.x;
  if (k >= NUM_EMB) return;
  const float* row = cb + k * EMB_DIM;
  float r[8];
#pragma unroll
  for (int j = 0; j < 8; ++j) r[j] = __fmul_rn(row[j], row[j]);
#pragma unroll
  for (int i = 8; i < 64; i += 8)
#pragma unroll
    for (int j = 0; j < 8; ++j)
      r[j] = __fadd_rn(r[j], __fmul_rn(row[i + j], row[i + j]));
  norms[k] = __fadd_rn(
      __fadd_rn(__fadd_rn(r[0], r[1]), __fadd_rn(r[2], r[3])),
      __fadd_rn(__fadd_rn(r[4], r[5]), __fadd_rn(r[6], r[7])));
}

// ---------------------------------------------------------------------------
// Kernel 2: main VQ. One thread per (b,t). x row in VGPRs; codebook rows read
// with WAVE-UNIFORM addresses -> compiler selects s_load (SMEM pipe), so the
// inner loop is pure VALU: v_mul_f32 v,s,v + v_add_f32 (sequential np chain).
// Bit-exact numpy fp32 replication:
//   E_k: sequential ascending-d  acc = fl(acc + fl(x_d*c_d))   (no fma)
//   d_k = fl(fl(A - fl(2*E_k)) + C_k);  argmin = first occurrence.
// ---------------------------------------------------------------------------
__global__ __launch_bounds__(256) void vq_main(
    const float* __restrict__ x,
    const float* __restrict__ cb,
    const float* __restrict__ norms,
    float* __restrict__ out) {
  const int tid = threadIdx.x;
  const int p   = blockIdx.x * 256 + tid;     // position in [0, B*T)
  const int b   = p >> 13;
  const int t   = p & (TT - 1);

  // ---- x[b,:,t] into registers (coalesced across lanes for each d) ----
  float xr[EMB_DIM];
  const float* xb = x + (size_t)b * EMB_DIM * TT + t;
#pragma unroll
  for (int d = 0; d < EMB_DIM; ++d) xr[d] = xb[(size_t)d * TT];

  // ---- A = np pairwise sum of squares ----
  float A;
  {
    float r[8];
#pragma unroll
    for (int j = 0; j < 8; ++j) r[j] = __fmul_rn(xr[j], xr[j]);
#pragma unroll
    for (int i = 8; i < 64; i += 8)
#pragma unroll
      for (int j = 0; j < 8; ++j)
        r[j] = __fadd_rn(r[j], __fmul_rn(xr[i + j], xr[i + j]));
    A = __fadd_rn(
        __fadd_rn(__fadd_rn(r[0], r[1]), __fadd_rn(r[2], r[3])),
        __fadd_rn(__fadd_rn(r[4], r[5]), __fadd_rn(r[6], r[7])));
  }

  float dmin = INFINITY;
  int best = 0;

  // ---- k loop: 4 rows interleaved (4 indep add chains for ILP).
  //      All codebook/norm addresses are wave-uniform -> scalar loads. ----
  for (int kb = 0; kb < NUM_EMB; kb += 4) {
    const vf4* cblk = (const vf4*)(cb + kb * EMB_DIM);  // 4 rows = 1KB contig
    float a0 = 0.f, a1 = 0.f, a2 = 0.f, a3 = 0.f;
#pragma unroll
    for (int d4 = 0; d4 < 16; ++d4) {
      vf4 c0 = cblk[d4];
      vf4 c1 = cblk[16 + d4];
      vf4 c2 = cblk[32 + d4];
      vf4 c3 = cblk[48 + d4];
      const int d = d4 * 4;
      a0 = __fadd_rn(a0, __fmul_rn(xr[d + 0], c0.x));
      a0 = __fadd_rn(a0, __fmul_rn(xr[d + 1], c0.y));
      a0 = __fadd_rn(a0, __fmul_rn(xr[d + 2], c0.z));
      a0 = __fadd_rn(a0, __fmul_rn(xr[d + 3], c0.w));
      a1 = __fadd_rn(a1, __fmul_rn(xr[d + 0], c1.x));
      a1 = __fadd_rn(a1, __fmul_rn(xr[d + 1], c1.y));
      a1 = __fadd_rn(a1, __fmul_rn(xr[d + 2], c1.z));
      a1 = __fadd_rn(a1, __fmul_rn(xr[d + 3], c1.w));
      a2 = __fadd_rn(a2, __fmul_rn(xr[d + 0], c2.x));
      a2 = __fadd_rn(a2, __fmul_rn(xr[d + 1], c2.y));
      a2 = __fadd_rn(a2, __fmul_rn(xr[d + 2], c2.z));
      a2 = __fadd_rn(a2, __fmul_rn(xr[d + 3], c2.w));
      a3 = __fadd_rn(a3, __fmul_rn(xr[d + 0], c3.x));
      a3 = __fadd_rn(a3, __fmul_rn(xr[d + 1], c3.y));
      a3 = __fadd_rn(a3, __fmul_rn(xr[d + 2], c3.z));
      a3 = __fadd_rn(a3, __fmul_rn(xr[d + 3], c3.w));
    }
    const vf4 cn = *(const vf4*)(norms + kb);  // uniform -> s_load_dwordx4
    float d0 = __fadd_rn(__fsub_rn(A, __fmul_rn(2.0f, a0)), cn.x);
    float d1 = __fadd_rn(__fsub_rn(A, __fmul_rn(2.0f, a1)), cn.y);
    float d2 = __fadd_rn(__fsub_rn(A, __fmul_rn(2.0f, a2)), cn.z);
    float d3 = __fadd_rn(__fsub_rn(A, __fmul_rn(2.0f, a3)), cn.w);
    if (d0 < dmin) { dmin = d0; best = kb; }
    if (d1 < dmin) { dmin = d1; best = kb + 1; }
    if (d2 < dmin) { dmin = d2; best = kb + 2; }
    if (d3 < dmin) { dmin = d3; best = kb + 3; }
  }

  // ---- gather winning row (divergent -> vector loads), write both outs ----
  const vf4* qrow = (const vf4*)(cb + best * EMB_DIM);
  float* o0 = out + (size_t)b * EMB_DIM * TT + t;
  float* o1 = o0 + (size_t)BB * EMB_DIM * TT;
#pragma unroll
  for (int j = 0; j < 16; ++j) {
    vf4 q = qrow[j];
    size_t d0 = (size_t)(4 * j) * TT;
    o0[d0]          = q.x; o1[d0]          = q.x;
    o0[d0 + TT]     = q.y; o1[d0 + TT]     = q.y;
    o0[d0 + 2 * TT] = q.z; o1[d0 + 2 * TT] = q.z;
    o0[d0 + 3 * TT] = q.w; o1[d0 + 3 * TT] = q.w;
  }
}

extern "C" void kernel_launch(void* const* d_in, const int* in_sizes, int n_in,
                              void* d_out, int out_size, void* d_ws, size_t ws_size,
                              hipStream_t stream) {
  const float* x  = (const float*)d_in[0];   // [16, 64, 8192]
  const float* cb = (const float*)d_in[1];   // [512, 64]
  float* out    = (float*)d_out;             // 2 x [16, 64, 8192]
  float* norms  = (float*)d_ws;              // 512 floats scratch
  vq_norms<<<2, 256, 0, stream>>>(cb, norms);
  vq_main<<<(BB * TT) / 256, 256, 0, stream>>>(x, cb, norms, out);
}

// Round 6
// 243.020 us; speedup vs baseline: 1.5359x; 1.5324x over previous
//
#include <hip/hip_runtime.h>
#include <math.h>
#include <stdint.h>

#define NUM_EMB 512
#define EMB_DIM 64
#define BB 16
#define TT 8192
#define BT (BB * TT)               // 131072 positions

typedef float vf4  __attribute__((ext_vector_type(4)));
typedef float vf64 __attribute__((ext_vector_type(64)));

// ---------------------------------------------------------------------------
// Kernel 1: numpy-pairwise codebook norms C_k -> ws (scalar-loadable later).
// np.sum(row*row,-1), n=64: 8 stride-8 accumulators, ((r0+r1)+(r2+r3))+(...).
// ---------------------------------------------------------------------------
__global__ __launch_bounds__(256) void vq_norms(const float* __restrict__ cb,
                                                float* __restrict__ norms) {
  const int k = blockIdx.x * 256 + threadIdx.x;
  if (k >= NUM_EMB) return;
  const float* row = cb + k * EMB_DIM;
  float r[8];
#pragma unroll
  for (int j = 0; j < 8; ++j) r[j] = __fmul_rn(row[j], row[j]);
#pragma unroll
  for (int i = 8; i < 64; i += 8)
#pragma unroll
    for (int j = 0; j < 8; ++j)
      r[j] = __fadd_rn(r[j], __fmul_rn(row[i + j], row[i + j]));
  norms[k] = __fadd_rn(
      __fadd_rn(__fadd_rn(r[0], r[1]), __fadd_rn(r[2], r[3])),
      __fadd_rn(__fadd_rn(r[4], r[5]), __fadd_rn(r[6], r[7])));
}

// ---------------------------------------------------------------------------
// Kernel 2: half-codebook argmin. blockIdx = (pos_block << 1) | half.
// Each thread: one (b,t) position, scans 256 codewords with bit-exact numpy
// fp32 chains (sequential ascending-d acc = fl(acc + fl(x_d*c_d)); no fma;
// d_k = fl(fl(A - fl(2E)) + C)). Codebook via wave-uniform s_load; x row in
// a single vf64 SSA value (cannot be demoted to scratch). Result packed as
// (float_bits(dmin)<<32)|k -> u64 min == (dist, first-k) lexicographic min.
// ---------------------------------------------------------------------------
__global__ __launch_bounds__(256, 4) void vq_half(
    const float* __restrict__ x,
    const float* __restrict__ cb,
    const float* __restrict__ norms,
    uint64_t* __restrict__ cand) {
  const int tid  = threadIdx.x;
  const int half = blockIdx.x & 1;
  const int p    = (blockIdx.x >> 1) * 256 + tid;   // position in [0, B*T)
  const int b    = p >> 13;
  const int t    = p & (TT - 1);
  const int kbase = half << 8;                      // 0 or 256

  // ---- x[b,:,t] into a register vector (coalesced per-d across lanes) ----
  vf64 xr;
  const float* xb = x + (size_t)b * EMB_DIM * TT + t;
#pragma unroll
  for (int d = 0; d < 64; ++d) xr[d] = xb[(size_t)d * TT];

  // ---- A = numpy pairwise sum of squares ----
  float A;
  {
    float r[8];
#pragma unroll
    for (int j = 0; j < 8; ++j) r[j] = __fmul_rn(xr[j], xr[j]);
#pragma unroll
    for (int i = 8; i < 64; i += 8)
#pragma unroll
      for (int j = 0; j < 8; ++j)
        r[j] = __fadd_rn(r[j], __fmul_rn(xr[i + j], xr[i + j]));
    A = __fadd_rn(
        __fadd_rn(__fadd_rn(r[0], r[1]), __fadd_rn(r[2], r[3])),
        __fadd_rn(__fadd_rn(r[4], r[5]), __fadd_rn(r[6], r[7])));
  }

  float dmin = INFINITY;
  int best = kbase;

  // ---- 256 codewords, 2 rows/iter (32 data SGPRs -> prefetch headroom) ----
  const float* base = cb + (size_t)kbase * EMB_DIM;
  for (int kb = 0; kb < 256; kb += 2) {
    const vf4* r0 = (const vf4*)(base + (size_t)kb * EMB_DIM);
    const vf4* r1 = r0 + 16;
    float a0 = 0.f, a1 = 0.f;
#pragma unroll
    for (int d4 = 0; d4 < 16; ++d4) {
      vf4 c0 = r0[d4];
      vf4 c1 = r1[d4];
      const int d = d4 * 4;
      a0 = __fadd_rn(a0, __fmul_rn(xr[d + 0], c0.x));
      a0 = __fadd_rn(a0, __fmul_rn(xr[d + 1], c0.y));
      a0 = __fadd_rn(a0, __fmul_rn(xr[d + 2], c0.z));
      a0 = __fadd_rn(a0, __fmul_rn(xr[d + 3], c0.w));
      a1 = __fadd_rn(a1, __fmul_rn(xr[d + 0], c1.x));
      a1 = __fadd_rn(a1, __fmul_rn(xr[d + 1], c1.y));
      a1 = __fadd_rn(a1, __fmul_rn(xr[d + 2], c1.z));
      a1 = __fadd_rn(a1, __fmul_rn(xr[d + 3], c1.w));
    }
    const float2 nn = *(const float2*)(norms + kbase + kb);  // s_load_dwordx2
    float d0 = __fadd_rn(__fsub_rn(A, __fmul_rn(2.0f, a0)), nn.x);
    float d1 = __fadd_rn(__fsub_rn(A, __fmul_rn(2.0f, a1)), nn.y);
    if (d0 < dmin) { dmin = d0; best = kbase + kb; }
    if (d1 < dmin) { dmin = d1; best = kbase + kb + 1; }
  }

  // distances here are always > 0 (||x||^2 ~ 64 dominates), so float bit
  // pattern is order-preserving as unsigned.
  cand[(size_t)half * BT + p] =
      ((uint64_t)__float_as_uint(dmin) << 32) | (uint32_t)best;
}

// ---------------------------------------------------------------------------
// Kernel 3: combine the two half-candidates (u64 min = dist-then-lowest-k),
// gather the winning codebook row, write both outputs.
// ---------------------------------------------------------------------------
__global__ __launch_bounds__(256) void vq_combine(
    const float* __restrict__ cb,
    const uint64_t* __restrict__ cand,
    float* __restrict__ out) {
  const int p = blockIdx.x * 256 + threadIdx.x;
  const int b = p >> 13;
  const int t = p & (TT - 1);

  const uint64_t c0 = cand[p];
  const uint64_t c1 = cand[(size_t)BT + p];
  const uint64_t m  = (c0 <= c1) ? c0 : c1;
  const int best = (int)(uint32_t)m;

  const vf4* qrow = (const vf4*)(cb + best * EMB_DIM);
  float* o0 = out + (size_t)b * EMB_DIM * TT + t;
  float* o1 = o0 + (size_t)BB * EMB_DIM * TT;
#pragma unroll
  for (int j = 0; j < 16; ++j) {
    vf4 q = qrow[j];
    size_t d0 = (size_t)(4 * j) * TT;
    o0[d0]          = q.x; o1[d0]          = q.x;
    o0[d0 + TT]     = q.y; o1[d0 + TT]     = q.y;
    o0[d0 + 2 * TT] = q.z; o1[d0 + 2 * TT] = q.z;
    o0[d0 + 3 * TT] = q.w; o1[d0 + 3 * TT] = q.w;
  }
}

extern "C" void kernel_launch(void* const* d_in, const int* in_sizes, int n_in,
                              void* d_out, int out_size, void* d_ws, size_t ws_size,
                              hipStream_t stream) {
  const float* x  = (const float*)d_in[0];   // [16, 64, 8192]
  const float* cb = (const float*)d_in[1];   // [512, 64]
  float* out = (float*)d_out;                // 2 x [16, 64, 8192]

  uint64_t* cand  = (uint64_t*)d_ws;                      // 2*BT u64 = 2 MB
  float*    norms = (float*)((char*)d_ws + (size_t)2 * BT * 8);  // 512 f32

  vq_norms<<<2, 256, 0, stream>>>(cb, norms);
  vq_half<<<(BT / 256) * 2, 256, 0, stream>>>(x, cb, norms, cand);
  vq_combine<<<BT / 256, 256, 0, stream>>>(cb, cand, out);
}